// Round 11
// baseline (271.853 us; speedup 1.0000x reference)
//
#include <hip/hip_runtime.h>
#include <math.h>

#define NEG_SLOPE 0.2f
#define BSHIFT 8            // 256 nodes per bucket
#define MAXBUK 512          // supports N up to 131072

typedef __attribute__((ext_vector_type(8))) short short8;   // 8 bf16 (MFMA A/B frag)
typedef __attribute__((ext_vector_type(4))) float floatx4;  // MFMA C/D frag
typedef __attribute__((ext_vector_type(2))) float floatx2;

static __device__ __forceinline__ float lrelu_exp(float e) {
    e = fmaxf(e, NEG_SLOPE * e);
    return __expf(e);
}

// fp32 -> bf16 (round-to-nearest-even)
static __device__ __forceinline__ short f2bf(float f) {
    union { float f; unsigned u; } v; v.f = f;
    unsigned r = v.u + 0x7FFFu + ((v.u >> 16) & 1u);
    return (short)(r >> 16);
}
// bf16 bits -> fp32 (exact)
static __device__ __forceinline__ float bf2f(unsigned short s) {
    union { float f; unsigned u; } v;
    v.u = ((unsigned)s) << 16;
    return v.f;
}
// split f into hi+lo bf16 pair (covers ~16 mantissa bits)
static __device__ __forceinline__ void splitbf(float f, short& hi, short& lo) {
    hi = f2bf(f);
    lo = f2bf(f - bf2f((unsigned short)hi));
}
// fp32 -> fp8 e4m3 byte (HW cvt; OCP on gfx950, self-consistent with decode)
static __device__ __forceinline__ unsigned char f2fp8(float f) {
    int e = __builtin_amdgcn_cvt_pk_fp8_f32(f, f, 0, false);
    return (unsigned char)(e & 0xff);
}

// ================= CSR build: LDS-bucketed partition (no global data atomics) =================
// R22: reverted to the R19 launcher shape. Both pfuse attempts (R20 512t, R21 256t) compiled
// gemm1 into a 40-52 VGPR envelope (spill; MfmaUtil ~1%) when partition_body shared the
// kernel. fine+splitW2+gemm1 (R19 k_fuse) compiles clean. NT hints added on streaming
// read-once arrays (dst/src, y1b) to protect gather-set L2 residency.

__global__ __launch_bounds__(512) void k_hist(const int* __restrict__ dst, int E, int CHUNK,
                                              int NBLK, int NBUK, int* __restrict__ blockhist) {
    __shared__ int hist[MAXBUK];
    int t = threadIdx.x, b = blockIdx.x;
    for (int i = t; i < NBUK; i += 512) hist[i] = 0;
    __syncthreads();
    int e0 = b * CHUNK, e1 = e0 + CHUNK; if (e1 > E) e1 = E;
    for (int e = e0 + t; e < e1; e += 512)
        atomicAdd(&hist[__builtin_nontemporal_load(dst + e) >> BSHIFT], 1);
    __syncthreads();
    for (int i = t; i < NBUK; i += 512) blockhist[(size_t)i * NBLK + b] = hist[i];
}

// Per-bucket LOCAL exclusive scan across NBLK block-counts (carry loop), writes bucket total.
__global__ __launch_bounds__(256) void k_colscan(int* __restrict__ blockhist,
                                                 int* __restrict__ btot, int NBLK) {
    int bucket = blockIdx.x, t = threadIdx.x;
    int lane = t & 63, wv = t >> 6;
    __shared__ int wsum[4];
    __shared__ int carry_s;
    if (t == 0) carry_s = 0;
    __syncthreads();
    for (int base = 0; base < NBLK; base += 256) {
        int idx = base + t;
        int v = (idx < NBLK) ? blockhist[(size_t)bucket * NBLK + idx] : 0;
        int s = v;
#pragma unroll
        for (int o = 1; o < 64; o <<= 1) {
            int u = __shfl_up(s, o, 64);
            if (lane >= o) s += u;
        }
        if (lane == 63) wsum[wv] = s;
        __syncthreads();
        int b0 = 0;
#pragma unroll
        for (int w = 0; w < 4; ++w) b0 += (w < wv) ? wsum[w] : 0;
        int excl = s + b0 - v + carry_s;
        if (idx < NBLK) blockhist[(size_t)bucket * NBLK + idx] = excl;
        __syncthreads();
        if (t == 255) carry_s += s + b0;   // chunk total
        __syncthreads();
    }
    if (t == 0) btot[bucket] = carry_s;
}

// Exclusive scan over NBUK bucket totals (NBUK <= 512).
__global__ __launch_bounds__(512) void k_bucket_scan(const int* __restrict__ btot,
                                                     int* __restrict__ bucketbase, int NBUK) {
    __shared__ int sh[512];
    int t = threadIdx.x;
    int v = (t < NBUK) ? btot[t] : 0;
    sh[t] = v;
    __syncthreads();
#pragma unroll
    for (int o = 1; o < 512; o <<= 1) {
        int u = (t >= o) ? sh[t - o] : 0;
        __syncthreads();
        sh[t] += u;
        __syncthreads();
    }
    if (t < NBUK) bucketbase[t] = sh[t] - v;
    if (t == NBUK - 1) bucketbase[NBUK] = sh[t];
}

// packed record: (src << 8) | (dst & 255)   [src < 2^24; bucket id recovers dst high bits]
__global__ __launch_bounds__(512) void k_partition(const int* __restrict__ src,
                                                   const int* __restrict__ dst, int E, int CHUNK,
                                                   int NBLK, int NBUK,
                                                   const int* __restrict__ blockhist,
                                                   const int* __restrict__ bucketbase,
                                                   unsigned* __restrict__ packed) {
    __shared__ int cur[MAXBUK];
    int t = threadIdx.x, b = blockIdx.x;
    for (int i = t; i < NBUK; i += 512)
        cur[i] = blockhist[(size_t)i * NBLK + b] + bucketbase[i];
    __syncthreads();
    int e0 = b * CHUNK, e1 = e0 + CHUNK; if (e1 > E) e1 = E;
    for (int e = e0 + t; e < e1; e += 512) {
        int d = __builtin_nontemporal_load(dst + e);
        int s = __builtin_nontemporal_load(src + e);
        int pos = atomicAdd(&cur[d >> BSHIFT], 1);
        packed[pos] = ((unsigned)s << 8) | ((unsigned)d & 255u);
    }
}

// ---------------- fused: k_fine + splitW2 + sentinel + gemm1 (R19 shape; compiles clean) -----

static __device__ void fine_body(const unsigned* __restrict__ packed,
                                 const int* __restrict__ bucketbase,
                                 int* __restrict__ offsets,
                                 int* __restrict__ csr_src,
                                 int N, int NBUK, int bucket) {
    __shared__ int fcnt[256];
    __shared__ int wsum[4];
    int t = threadIdx.x;
    int lo = bucket << BSHIFT;
    int nn = N - lo; if (nn > 256) nn = 256;
    int ebase = bucketbase[bucket];
    int ecnt = bucketbase[bucket + 1] - ebase;
    fcnt[t] = 0;
    __syncthreads();
    for (int i = t; i < ecnt; i += 256) {
        unsigned p = packed[ebase + i];
        atomicAdd(&fcnt[p & 255u], 1);
    }
    __syncthreads();
    int v = fcnt[t];
    int lane = t & 63, wv = t >> 6;
    int s = v;
#pragma unroll
    for (int o = 1; o < 64; o <<= 1) {
        int u = __shfl_up(s, o, 64);
        if (lane >= o) s += u;
    }
    if (lane == 63) wsum[wv] = s;
    __syncthreads();
    int base = 0;
#pragma unroll
    for (int w = 0; w < 4; ++w) base += (w < wv) ? wsum[w] : 0;
    int excl = s + base - v;
    if (t < nn) offsets[lo + t] = ebase + excl;
    if (bucket == NBUK - 1 && t == 0) offsets[N] = ebase + ecnt;  // == E
    __syncthreads();
    fcnt[t] = excl;   // reuse as cursor
    __syncthreads();
    for (int i = t; i < ecnt; i += 256) {
        unsigned p = packed[ebase + i];
        int pos = atomicAdd(&fcnt[p & 255u], 1);
        csr_src[ebase + pos] = (int)(p >> 8);
    }
}

static __device__ void splitW2_body(const float* __restrict__ W2,
                                    short* __restrict__ w2h,
                                    short* __restrict__ w2l, int bid) {
    int i = bid * 256 + (int)threadIdx.x;
    if (i < 64 * 48) {
        int row = i / 48, col = i % 48;
        short hi = 0, lo = 0;
        if (col < 40) splitbf(W2[row * 40 + col], hi, lo);
        w2h[i] = hi; w2l[i] = lo;
    }
}

// Sentinel row pk1[N]: a_src = -1e30 (-> lrelu_exp = 0 exactly), msg bytes = 0.
static __device__ void dummy_body(unsigned char* __restrict__ pk1, int N) {
    int t = threadIdx.x;
    if (t < 32) {
        unsigned v = ((t & 3) == 0) ? __float_as_uint(-1e30f) : 0u;
        *(unsigned*)(pk1 + (size_t)N * 128 + t * 4) = v;
    }
}

// Layer 1 GEMM via MFMA bf16.  Output = combined 128 B node rows pk1: per head h (0..7),
// 16 B chunk [fp32 a_src(h) | 8 x fp8 msg | 4 B pad].  One row = one cache line.
static __device__ void gemm1_body(const float* __restrict__ x,
                                  const float* __restrict__ W1,
                                  const float* __restrict__ att_s,
                                  const float* __restrict__ att_d,
                                  unsigned char* __restrict__ pk1,
                                  float* __restrict__ a_d1, int N, int gblk) {
    int tid = threadIdx.x, wave = tid >> 6, lane = tid & 63;
    int n16 = lane & 15, q = lane >> 4;
    int nb = gblk * 64 + wave * 16;
    if (nb >= N) return;

    short8 bfr[4][4];
#pragma unroll
    for (int ct = 0; ct < 4; ++ct) {
        int n = ct * 16 + n16;
#pragma unroll
        for (int kc = 0; kc < 4; ++kc) {
            int k0 = kc * 32 + q * 8;
            short8 b;
#pragma unroll
            for (int j = 0; j < 8; ++j) b[j] = f2bf(W1[(k0 + j) * 64 + n]);
            bfr[ct][kc] = b;
        }
    }

    int arow = nb + n16; if (arow >= N) arow = N - 1;
    const float* xr = x + (size_t)arow * 128 + q * 8;
    short8 afr[4];
#pragma unroll
    for (int kc = 0; kc < 4; ++kc) {
        float4 u0 = *(const float4*)(xr + kc * 32);
        float4 u1 = *(const float4*)(xr + kc * 32 + 4);
        short8 a;
        a[0] = f2bf(u0.x); a[1] = f2bf(u0.y); a[2] = f2bf(u0.z); a[3] = f2bf(u0.w);
        a[4] = f2bf(u1.x); a[5] = f2bf(u1.y); a[6] = f2bf(u1.z); a[7] = f2bf(u1.w);
        afr[kc] = a;
    }

    floatx4 acc[4];
#pragma unroll
    for (int ct = 0; ct < 4; ++ct) {
        floatx4 c = {0.f, 0.f, 0.f, 0.f};
#pragma unroll
        for (int kc = 0; kc < 4; ++kc)
            c = __builtin_amdgcn_mfma_f32_16x16x32_bf16(afr[kc], bfr[ct][kc], c, 0, 0, 0);
        acc[ct] = c;
    }

    // message fp8 bytes: channel c = ct*16+n16 -> head h=c>>3, byte h*16 + 4 + (c&7)
#pragma unroll
    for (int ct = 0; ct < 4; ++ct) {
        int h = 2 * ct + (n16 >> 3);
        int cin = n16 & 7;
#pragma unroll
        for (int r = 0; r < 4; ++r) {
            int row = nb + q * 4 + r;
            if (row < N) pk1[(size_t)row * 128 + h * 16 + 4 + cin] = f2fp8(acc[ct][r]);
        }
    }

    // attention logits: a_src fp32 into pk1 chunk head, a_dst fp32 separate
#pragma unroll
    for (int ct = 0; ct < 4; ++ct) {
        float as = att_s[ct * 16 + n16];
        float adv = att_d[ct * 16 + n16];
#pragma unroll
        for (int r = 0; r < 4; ++r) {
            float ps = acc[ct][r] * as;
            float pd = acc[ct][r] * adv;
#pragma unroll
            for (int m = 1; m < 8; m <<= 1) {
                ps += __shfl_xor(ps, m, 64);
                pd += __shfl_xor(pd, m, 64);
            }
            int row = nb + q * 4 + r;
            if ((n16 & 7) == 0 && row < N) {
                int h = 2 * ct + (n16 >> 3);
                a_d1[row * 8 + h] = pd;
                *(float*)(pk1 + (size_t)row * 128 + h * 16) = ps;
            }
        }
    }
}

__global__ __launch_bounds__(256) void k_fuse(const unsigned* __restrict__ packed,
                                              const int* __restrict__ bucketbase,
                                              int* __restrict__ offsets,
                                              int* __restrict__ csr_src,
                                              int N, int NBUK,
                                              const float* __restrict__ W2,
                                              short* __restrict__ w2h,
                                              short* __restrict__ w2l,
                                              const float* __restrict__ x,
                                              const float* __restrict__ W1,
                                              const float* __restrict__ as1,
                                              const float* __restrict__ ad1,
                                              unsigned char* __restrict__ pk1,
                                              float* __restrict__ a_d1) {
    int b = blockIdx.x;
    if (b < NBUK)                fine_body(packed, bucketbase, offsets, csr_src, N, NBUK, b);
    else if (b < NBUK + 12)      splitW2_body(W2, w2h, w2l, b - NBUK);
    else if (b == NBUK + 12)     dummy_body(pk1, N);
    else                         gemm1_body(x, W1, as1, ad1, pk1, a_d1, N, b - NBUK - 13);
}

// ---------------- Layer 1 aggregation: 4-deep pipeline + sentinel + packed f32x2 FMA ---------
__global__ __launch_bounds__(256) void k_agg1(const unsigned char* __restrict__ pk1,
                                              const float* __restrict__ a_d1,
                                              const int* __restrict__ offsets,
                                              const int* __restrict__ csr_src,
                                              const float* __restrict__ b1,
                                              unsigned short* __restrict__ y1b, int N) {
    int wave = threadIdx.x >> 6, lane = threadIdx.x & 63;
    int l32 = lane & 31;         // lane within half
    int e4  = l32 >> 3;          // edge slot (0..3)
    int c8  = l32 & 7;           // head index; owns channels 8*c8 .. 8*c8+7
    int hb  = lane & 32;         // shfl base of this half
    int d = blockIdx.x * 8 + wave * 2 + (lane >> 5);
    bool dval = (d < N);
    int dd = dval ? d : N - 1;   // clamp for safe loads; stores predicated on dval
    float ad = a_d1[dd * 8 + c8];
    floatx2 acc2[4];
#pragma unroll
    for (int k = 0; k < 4; ++k) acc2[k] = (floatx2){0.f, 0.f};
    float wsum = 0.f;
    if (e4 == 0) {               // self-loop handled by edge-slot 0 (8 lanes per half = 8 heads)
        uint4 v = *(const uint4*)(pk1 + (size_t)dd * 128 + c8 * 16);
        float w0 = lrelu_exp(__uint_as_float(v.x) + ad);
        wsum = w0;
        acc2[0] = __builtin_amdgcn_cvt_pk_f32_fp8((int)v.y, false) * w0;
        acc2[1] = __builtin_amdgcn_cvt_pk_f32_fp8((int)v.y, true)  * w0;
        acc2[2] = __builtin_amdgcn_cvt_pk_f32_fp8((int)v.z, false) * w0;
        acc2[3] = __builtin_amdgcn_cvt_pk_f32_fp8((int)v.z, true)  * w0;
    }
    int i0 = offsets[dd], i1 = offsets[dd + 1];
    // Halves may run different trip counts (divergent); all __shfl sources stay within the
    // active half, so inactive-lane reads never occur.
    for (int base = i0; base < i1; base += 32) {
        int idx = base + l32;
        int sv = (idx < i1) ? __builtin_nontemporal_load(csr_src + idx) : N;  // sentinel
        int mh = i1 - base; if (mh > 32) mh = 32;
        // prologue: issue j=0 group's 2 gathers
        int sA = __shfl(sv, hb + e4, 64);
        int sB = __shfl(sv, hb + 4 + e4, 64);
        uint4 vA = *(const uint4*)(pk1 + (size_t)sA * 128 + c8 * 16);
        uint4 vB = *(const uint4*)(pk1 + (size_t)sB * 128 + c8 * 16);
        for (int j = 0; j < mh; j += 8) {
            // prefetch j+8 group (clamped; never consumed if clamped)
            int iC = hb + ((j + 8 + e4 < 32) ? (j + 8 + e4) : 31);
            int iD = hb + ((j + 12 + e4 < 32) ? (j + 12 + e4) : 31);
            int sC = __shfl(sv, iC, 64);
            int sD = __shfl(sv, iD, 64);
            uint4 vC = *(const uint4*)(pk1 + (size_t)sC * 128 + c8 * 16);
            uint4 vD = *(const uint4*)(pk1 + (size_t)sD * 128 + c8 * 16);
            // consume current pair (sentinel rows: a_src=-1e30 -> w=0, msg=0)
            {
                float w = lrelu_exp(__uint_as_float(vA.x) + ad);
                wsum += w;
                acc2[0] = __builtin_amdgcn_cvt_pk_f32_fp8((int)vA.y, false) * w + acc2[0];
                acc2[1] = __builtin_amdgcn_cvt_pk_f32_fp8((int)vA.y, true)  * w + acc2[1];
                acc2[2] = __builtin_amdgcn_cvt_pk_f32_fp8((int)vA.z, false) * w + acc2[2];
                acc2[3] = __builtin_amdgcn_cvt_pk_f32_fp8((int)vA.z, true)  * w + acc2[3];
            }
            {
                float w = lrelu_exp(__uint_as_float(vB.x) + ad);
                wsum += w;
                acc2[0] = __builtin_amdgcn_cvt_pk_f32_fp8((int)vB.y, false) * w + acc2[0];
                acc2[1] = __builtin_amdgcn_cvt_pk_f32_fp8((int)vB.y, true)  * w + acc2[1];
                acc2[2] = __builtin_amdgcn_cvt_pk_f32_fp8((int)vB.z, false) * w + acc2[2];
                acc2[3] = __builtin_amdgcn_cvt_pk_f32_fp8((int)vB.z, true)  * w + acc2[3];
            }
            vA = vC; vB = vD;
        }
    }
    // combine the 4 edge slots within each half (xor 8,16 stays inside the half)
#pragma unroll
    for (int o = 8; o <= 16; o <<= 1) {
#pragma unroll
        for (int k = 0; k < 4; ++k) {
            acc2[k][0] += __shfl_xor(acc2[k][0], o, 64);
            acc2[k][1] += __shfl_xor(acc2[k][1], o, 64);
        }
        wsum += __shfl_xor(wsum, o, 64);
    }
    if (e4 == 0 && dval) {
        float inv = 1.f / (wsum + 1e-16f);
        short8 o8;
#pragma unroll
        for (int k = 0; k < 4; ++k) {
#pragma unroll
            for (int u = 0; u < 2; ++u) {
                float v = acc2[k][u] * inv + b1[c8 * 8 + 2 * k + u];
                v = v > 0.f ? v : expm1f(v);
                o8[2 * k + u] = f2bf(v);
            }
        }
        __builtin_nontemporal_store(o8, (short8*)(y1b + (size_t)d * 64 + c8 * 8));
    }
}

// ---------------- Layer 2 GEMM: y1 bf16 A-frags direct, W2 split-bf16; NT on y1b stream ------
__global__ __launch_bounds__(256) void k_gemm2(const unsigned short* __restrict__ y1b,
                                               const short* __restrict__ w2h,
                                               const short* __restrict__ w2l,
                                               const float* __restrict__ att_s,
                                               const float* __restrict__ att_d,
                                               unsigned char* __restrict__ h2b8,
                                               float* __restrict__ a2s,
                                               float* __restrict__ a2d, int N) {
    int tid = threadIdx.x, wave = tid >> 6, lane = tid & 63;
    int n16 = lane & 15, q = lane >> 4;
    int nb = blockIdx.x * 64 + wave * 16;
    if (nb >= N) return;

    int arow = nb + n16; if (arow >= N) arow = N - 1;
    const short8* yr = (const short8*)(y1b + (size_t)arow * 64 + q * 8);
    short8 a0 = __builtin_nontemporal_load(yr);
    short8 a1 = __builtin_nontemporal_load(yr + 4);   // +32 shorts

    float psr[4] = {0.f, 0.f, 0.f, 0.f}, pdr[4] = {0.f, 0.f, 0.f, 0.f};
#pragma unroll
    for (int ct = 0; ct < 3; ++ct) {
        int n = ct * 16 + n16;
        short8 bh0, bh1, bl0, bl1;
#pragma unroll
        for (int j = 0; j < 8; ++j) {
            int k0 = q * 8 + j;
            bh0[j] = w2h[k0 * 48 + n];
            bl0[j] = w2l[k0 * 48 + n];
            bh1[j] = w2h[(32 + k0) * 48 + n];
            bl1[j] = w2l[(32 + k0) * 48 + n];
        }
        floatx4 c = {0.f, 0.f, 0.f, 0.f};
        c = __builtin_amdgcn_mfma_f32_16x16x32_bf16(a0, bl0, c, 0, 0, 0);
        c = __builtin_amdgcn_mfma_f32_16x16x32_bf16(a1, bl1, c, 0, 0, 0);
        c = __builtin_amdgcn_mfma_f32_16x16x32_bf16(a0, bh0, c, 0, 0, 0);
        c = __builtin_amdgcn_mfma_f32_16x16x32_bf16(a1, bh1, c, 0, 0, 0);

        int col = ct * 16 + n16;
#pragma unroll
        for (int r = 0; r < 4; ++r) {
            int row = nb + q * 4 + r;
            if (col < 40 && row < N) h2b8[(size_t)row * 40 + col] = f2fp8(c[r]);
        }
        float asv = (col < 40) ? att_s[col] : 0.f;
        float adv = (col < 40) ? att_d[col] : 0.f;
#pragma unroll
        for (int r = 0; r < 4; ++r) {
            psr[r] = fmaf(c[r], asv, psr[r]);
            pdr[r] = fmaf(c[r], adv, pdr[r]);
        }
    }
#pragma unroll
    for (int r = 0; r < 4; ++r) {
        float ps = psr[r], pd = pdr[r];
#pragma unroll
        for (int m = 1; m < 16; m <<= 1) {
            ps += __shfl_xor(ps, m, 64);
            pd += __shfl_xor(pd, m, 64);
        }
        int row = nb + q * 4 + r;
        if (n16 == 0 && row < N) { a2s[row] = ps; a2d[row] = pd; }
    }
}

// ---------------- Layer 2 aggregation: 4-deep pipeline, mask-free, packed f32x2 FMA ----------
__global__ __launch_bounds__(256) void k_agg2(const unsigned char* __restrict__ h2b8,
                                              const float* __restrict__ a2s,
                                              const float* __restrict__ a2d,
                                              const int* __restrict__ offsets,
                                              const int* __restrict__ csr_src,
                                              const float* __restrict__ b2,
                                              float* __restrict__ out, int N) {
    int wave = threadIdx.x >> 6, lane = threadIdx.x & 63;
    int l32 = lane & 31;
    int hb  = lane & 32;              // shfl base of this half
    int t   = l32 / 10;               // edge slot 0..2; t==3 -> lanes 30,31 (acc unused)
    int c10 = l32 % 10;               // channel quad 4*c10 .. 4*c10+3
    int d = blockIdx.x * 8 + wave * 2 + (lane >> 5);
    bool dval = (d < N);
    int dd = dval ? d : N - 1;
    float ad = a2d[dd];
    float w0 = lrelu_exp(a2s[dd] + ad);
    floatx2 acc2[2];
    acc2[0] = (floatx2){0.f, 0.f}; acc2[1] = (floatx2){0.f, 0.f};
    if (t == 0) {                     // self-loop on slot 0 (10 lanes cover 40 channels)
        unsigned v = *(const unsigned*)(h2b8 + (size_t)dd * 40 + c10 * 4);
        acc2[0] = __builtin_amdgcn_cvt_pk_f32_fp8((int)v, false) * w0;
        acc2[1] = __builtin_amdgcn_cvt_pk_f32_fp8((int)v, true)  * w0;
    }
    float wsum_l = 0.f;
    int i0 = offsets[dd], i1 = offsets[dd + 1];
    for (int base = i0; base < i1; base += 30) {
        int m = i1 - base; if (m > 30) m = 30;
        int sv = 0; float wv = 0.f;
        if (l32 < m) {
            sv = __builtin_nontemporal_load(csr_src + base + l32);
            wv = lrelu_exp(a2s[sv] + ad);
        }
        wsum_l += wv;
        // prologue: issue j=0 pair (slots t, 3+t)
        int sA = __shfl(sv, hb + t, 64);
        int sB = __shfl(sv, hb + 3 + t, 64);
        float wA = __shfl(wv, hb + t, 64);
        float wB = __shfl(wv, hb + 3 + t, 64);
        unsigned vA = *(const unsigned*)(h2b8 + (size_t)sA * 40 + c10 * 4);
        unsigned vB = *(const unsigned*)(h2b8 + (size_t)sB * 40 + c10 * 4);
        for (int j = 0; j < m; j += 6) {
            // prefetch j+6 pair (clamped; clamped ones never consumed, and slot 31 has wv=0)
            int iC = hb + ((j + 6 + t < 32) ? (j + 6 + t) : 31);
            int iD = hb + ((j + 9 + t < 32) ? (j + 9 + t) : 31);
            int sC = __shfl(sv, iC, 64);
            int sD = __shfl(sv, iD, 64);
            float wC = __shfl(wv, iC, 64);
            float wD = __shfl(wv, iD, 64);
            unsigned vC = *(const unsigned*)(h2b8 + (size_t)sC * 40 + c10 * 4);
            unsigned vD = *(const unsigned*)(h2b8 + (size_t)sD * 40 + c10 * 4);
            acc2[0] = __builtin_amdgcn_cvt_pk_f32_fp8((int)vA, false) * wA + acc2[0];
            acc2[1] = __builtin_amdgcn_cvt_pk_f32_fp8((int)vA, true)  * wA + acc2[1];
            acc2[0] = __builtin_amdgcn_cvt_pk_f32_fp8((int)vB, false) * wB + acc2[0];
            acc2[1] = __builtin_amdgcn_cvt_pk_f32_fp8((int)vB, true)  * wB + acc2[1];
            vA = vC; vB = vD; wA = wC; wB = wD;
        }
    }
    // wsum over the half (xor strides < 32 stay inside the half)
#pragma unroll
    for (int mm = 1; mm < 32; mm <<= 1) wsum_l += __shfl_xor(wsum_l, mm, 64);
    float wsum = wsum_l + w0;
    // combine 3 edge slots: t==0 lanes gather from t=1 (+10) and t=2 (+20)
#pragma unroll
    for (int k = 0; k < 2; ++k) {
#pragma unroll
        for (int u = 0; u < 2; ++u) {
            float a = acc2[k][u];
            acc2[k][u] = a + __shfl(a, hb + c10 + 10, 64) + __shfl(a, hb + c10 + 20, 64);
        }
    }
    bool act = (t == 0) && dval;
    float inv = 1.f / (wsum + 1e-16f);
    float o[4], mx = -INFINITY;
#pragma unroll
    for (int k = 0; k < 4; ++k) {
        o[k] = act ? (acc2[k >> 1][k & 1] * inv + b2[c10 * 4 + k]) : -INFINITY;
        mx = fmaxf(mx, o[k]);
    }
#pragma unroll
    for (int mm = 1; mm < 32; mm <<= 1) mx = fmaxf(mx, __shfl_xor(mx, mm, 64));
    float ex = 0.f;
    if (act) {
#pragma unroll
        for (int k = 0; k < 4; ++k) ex += __expf(o[k] - mx);
    }
#pragma unroll
    for (int mm = 1; mm < 32; mm <<= 1) ex += __shfl_xor(ex, mm, 64);
    if (act) {
        float lse = __logf(ex);
        floatx4 o4 = {o[0] - mx - lse, o[1] - mx - lse, o[2] - mx - lse, o[3] - mx - lse};
        __builtin_nontemporal_store(o4, (floatx4*)(out + (size_t)d * 40 + c10 * 4));
    }
}

// ---------------- launcher ----------------

extern "C" void kernel_launch(void* const* d_in, const int* in_sizes, int n_in,
                              void* d_out, int out_size, void* d_ws, size_t ws_size,
                              hipStream_t stream) {
    const float* x   = (const float*)d_in[0];
    const int*   ei  = (const int*)d_in[1];
    const float* W1  = (const float*)d_in[2];
    const float* as1 = (const float*)d_in[3];
    const float* ad1 = (const float*)d_in[4];
    const float* b1  = (const float*)d_in[5];
    const float* W2  = (const float*)d_in[6];
    const float* as2 = (const float*)d_in[7];
    const float* ad2 = (const float*)d_in[8];
    const float* b2  = (const float*)d_in[9];
    float* out = (float*)d_out;

    int N = in_sizes[0] / 128;   // 100000
    int E = in_sizes[1] / 2;     // 1600000
    const int* src = ei;
    const int* dst = ei + E;

    int NBUK = (N + 255) >> BSHIFT;          // 391
    int CHUNK = 4096;
    int NBLK = (E + CHUNK - 1) / CHUNK;      // 391

    char* ws = (char*)d_ws;
    size_t off = 0;
    auto alloc = [&](size_t bytes) -> char* {
        char* p = ws + off;
        off += (bytes + 255) & ~(size_t)255;
        return p;
    };
    unsigned char* pk1 = (unsigned char*)alloc((size_t)(N + 1) * 128);  // + sentinel row
    float* a_d1    = (float*)alloc((size_t)N * 8 * 4);
    unsigned short* y1b = (unsigned short*)alloc((size_t)N * 64 * 2);   // bf16
    // h2b8 (fp8, 4 MB) and packed (uint, 6.4 MB) are temporally disjoint: share region.
    size_t shared_sz = (size_t)N * 40;
    if ((size_t)E * 4 > shared_sz) shared_sz = (size_t)E * 4;
    char*  region  = alloc(shared_sz);
    unsigned char* h2b8 = (unsigned char*)region;
    unsigned* packed    = (unsigned*)region;
    float* a2s     = (float*)alloc((size_t)N * 4);
    float* a2d     = (float*)alloc((size_t)N * 4);
    int*   offsets = (int*)alloc((size_t)(N + 1) * 4);
    int*   csr_src = (int*)alloc((size_t)E * 4);
    int*   blockhist  = (int*)alloc((size_t)NBUK * NBLK * 4);
    int*   btot       = (int*)alloc((size_t)NBUK * 4);
    int*   bucketbase = (int*)alloc((size_t)(NBUK + 1) * 4);
    short* w2h     = (short*)alloc((size_t)64 * 48 * 2);
    short* w2l     = (short*)alloc((size_t)64 * 48 * 2);

    int nb2 = (N + 7) / 8;   // agg kernels: 2 nodes per wave, 8 per block
    int gb = (N + 63) / 64;

    k_hist<<<NBLK, 512, 0, stream>>>(dst, E, CHUNK, NBLK, NBUK, blockhist);
    k_colscan<<<NBUK, 256, 0, stream>>>(blockhist, btot, NBLK);
    k_bucket_scan<<<1, 512, 0, stream>>>(btot, bucketbase, NBUK);
    k_partition<<<NBLK, 512, 0, stream>>>(src, dst, E, CHUNK, NBLK, NBUK, blockhist,
                                          bucketbase, packed);
    // fused: fine (NBUK) + splitW2 (12) + sentinel (1) + gemm1 (gb) — compiles gemm1 clean
    k_fuse<<<NBUK + 13 + gb, 256, 0, stream>>>(packed, bucketbase, offsets, csr_src, N, NBUK,
                                               W2, w2h, w2l, x, W1, as1, ad1,
                                               pk1, a_d1);
    k_agg1<<<nb2, 256, 0, stream>>>(pk1, a_d1, offsets, csr_src, b1, y1b, N);
    k_gemm2<<<gb, 256, 0, stream>>>(y1b, w2h, w2l, as2, ad2, h2b8, a2s, a2d, N);
    k_agg2<<<nb2, 256, 0, stream>>>(h2b8, a2s, a2d, offsets, csr_src, b2, out, N);
}

// Round 12
// 258.493 us; speedup vs baseline: 1.0517x; 1.0517x over previous
//
#include <hip/hip_runtime.h>
#include <math.h>

#define NEG_SLOPE 0.2f
#define BSHIFT 8            // 256 nodes per bucket
#define MAXBUK 512          // supports N up to 131072

typedef __attribute__((ext_vector_type(8))) short short8;   // 8 bf16 (MFMA A/B frag)
typedef __attribute__((ext_vector_type(4))) float floatx4;  // MFMA C/D frag
typedef __attribute__((ext_vector_type(2))) float floatx2;

static __device__ __forceinline__ float lrelu_exp(float e) {
    e = fmaxf(e, NEG_SLOPE * e);
    return __expf(e);
}

// fp32 -> bf16 (round-to-nearest-even)
static __device__ __forceinline__ short f2bf(float f) {
    union { float f; unsigned u; } v; v.f = f;
    unsigned r = v.u + 0x7FFFu + ((v.u >> 16) & 1u);
    return (short)(r >> 16);
}
// bf16 bits -> fp32 (exact)
static __device__ __forceinline__ float bf2f(unsigned short s) {
    union { float f; unsigned u; } v;
    v.u = ((unsigned)s) << 16;
    return v.f;
}
// split f into hi+lo bf16 pair (covers ~16 mantissa bits)
static __device__ __forceinline__ void splitbf(float f, short& hi, short& lo) {
    hi = f2bf(f);
    lo = f2bf(f - bf2f((unsigned short)hi));
}
// fp32 -> fp8 e4m3 byte (HW cvt; OCP on gfx950, self-consistent with decode)
static __device__ __forceinline__ unsigned char f2fp8(float f) {
    int e = __builtin_amdgcn_cvt_pk_fp8_f32(f, f, 0, false);
    return (unsigned char)(e & 0xff);
}

// ================= CSR build: LDS-bucketed partition (no global data atomics) =================
// R23: surgical revert of R22's NT hints on src/dst (dst is read TWICE — hist then partition —
// and src+dst fit in aggregate L2; NT bypassed that reuse: −12 us regression) and on y1b.
// NT retained ONLY on true single-use streams: csr_src loads, y1b/out stores.
// This restores the best measured configuration (259.8 us, R19/R21).

__global__ __launch_bounds__(512) void k_hist(const int* __restrict__ dst, int E, int CHUNK,
                                              int NBLK, int NBUK, int* __restrict__ blockhist) {
    __shared__ int hist[MAXBUK];
    int t = threadIdx.x, b = blockIdx.x;
    for (int i = t; i < NBUK; i += 512) hist[i] = 0;
    __syncthreads();
    int e0 = b * CHUNK, e1 = e0 + CHUNK; if (e1 > E) e1 = E;
    for (int e = e0 + t; e < e1; e += 512) atomicAdd(&hist[dst[e] >> BSHIFT], 1);
    __syncthreads();
    for (int i = t; i < NBUK; i += 512) blockhist[(size_t)i * NBLK + b] = hist[i];
}

// Per-bucket LOCAL exclusive scan across NBLK block-counts (carry loop), writes bucket total.
__global__ __launch_bounds__(256) void k_colscan(int* __restrict__ blockhist,
                                                 int* __restrict__ btot, int NBLK) {
    int bucket = blockIdx.x, t = threadIdx.x;
    int lane = t & 63, wv = t >> 6;
    __shared__ int wsum[4];
    __shared__ int carry_s;
    if (t == 0) carry_s = 0;
    __syncthreads();
    for (int base = 0; base < NBLK; base += 256) {
        int idx = base + t;
        int v = (idx < NBLK) ? blockhist[(size_t)bucket * NBLK + idx] : 0;
        int s = v;
#pragma unroll
        for (int o = 1; o < 64; o <<= 1) {
            int u = __shfl_up(s, o, 64);
            if (lane >= o) s += u;
        }
        if (lane == 63) wsum[wv] = s;
        __syncthreads();
        int b0 = 0;
#pragma unroll
        for (int w = 0; w < 4; ++w) b0 += (w < wv) ? wsum[w] : 0;
        int excl = s + b0 - v + carry_s;
        if (idx < NBLK) blockhist[(size_t)bucket * NBLK + idx] = excl;
        __syncthreads();
        if (t == 255) carry_s += s + b0;   // chunk total
        __syncthreads();
    }
    if (t == 0) btot[bucket] = carry_s;
}

// Exclusive scan over NBUK bucket totals (NBUK <= 512).
__global__ __launch_bounds__(512) void k_bucket_scan(const int* __restrict__ btot,
                                                     int* __restrict__ bucketbase, int NBUK) {
    __shared__ int sh[512];
    int t = threadIdx.x;
    int v = (t < NBUK) ? btot[t] : 0;
    sh[t] = v;
    __syncthreads();
#pragma unroll
    for (int o = 1; o < 512; o <<= 1) {
        int u = (t >= o) ? sh[t - o] : 0;
        __syncthreads();
        sh[t] += u;
        __syncthreads();
    }
    if (t < NBUK) bucketbase[t] = sh[t] - v;
    if (t == NBUK - 1) bucketbase[NBUK] = sh[t];
}

// packed record: (src << 8) | (dst & 255)   [src < 2^24; bucket id recovers dst high bits]
__global__ __launch_bounds__(512) void k_partition(const int* __restrict__ src,
                                                   const int* __restrict__ dst, int E, int CHUNK,
                                                   int NBLK, int NBUK,
                                                   const int* __restrict__ blockhist,
                                                   const int* __restrict__ bucketbase,
                                                   unsigned* __restrict__ packed) {
    __shared__ int cur[MAXBUK];
    int t = threadIdx.x, b = blockIdx.x;
    for (int i = t; i < NBUK; i += 512)
        cur[i] = blockhist[(size_t)i * NBLK + b] + bucketbase[i];
    __syncthreads();
    int e0 = b * CHUNK, e1 = e0 + CHUNK; if (e1 > E) e1 = E;
    for (int e = e0 + t; e < e1; e += 512) {
        int d = dst[e], s = src[e];
        int pos = atomicAdd(&cur[d >> BSHIFT], 1);
        packed[pos] = ((unsigned)s << 8) | ((unsigned)d & 255u);
    }
}

// ---------------- fused: k_fine + splitW2 + sentinel + gemm1 (compiles gemm1 clean) ----------

static __device__ void fine_body(const unsigned* __restrict__ packed,
                                 const int* __restrict__ bucketbase,
                                 int* __restrict__ offsets,
                                 int* __restrict__ csr_src,
                                 int N, int NBUK, int bucket) {
    __shared__ int fcnt[256];
    __shared__ int wsum[4];
    int t = threadIdx.x;
    int lo = bucket << BSHIFT;
    int nn = N - lo; if (nn > 256) nn = 256;
    int ebase = bucketbase[bucket];
    int ecnt = bucketbase[bucket + 1] - ebase;
    fcnt[t] = 0;
    __syncthreads();
    for (int i = t; i < ecnt; i += 256) {
        unsigned p = packed[ebase + i];
        atomicAdd(&fcnt[p & 255u], 1);
    }
    __syncthreads();
    int v = fcnt[t];
    int lane = t & 63, wv = t >> 6;
    int s = v;
#pragma unroll
    for (int o = 1; o < 64; o <<= 1) {
        int u = __shfl_up(s, o, 64);
        if (lane >= o) s += u;
    }
    if (lane == 63) wsum[wv] = s;
    __syncthreads();
    int base = 0;
#pragma unroll
    for (int w = 0; w < 4; ++w) base += (w < wv) ? wsum[w] : 0;
    int excl = s + base - v;
    if (t < nn) offsets[lo + t] = ebase + excl;
    if (bucket == NBUK - 1 && t == 0) offsets[N] = ebase + ecnt;  // == E
    __syncthreads();
    fcnt[t] = excl;   // reuse as cursor
    __syncthreads();
    for (int i = t; i < ecnt; i += 256) {
        unsigned p = packed[ebase + i];
        int pos = atomicAdd(&fcnt[p & 255u], 1);
        csr_src[ebase + pos] = (int)(p >> 8);
    }
}

static __device__ void splitW2_body(const float* __restrict__ W2,
                                    short* __restrict__ w2h,
                                    short* __restrict__ w2l, int bid) {
    int i = bid * 256 + (int)threadIdx.x;
    if (i < 64 * 48) {
        int row = i / 48, col = i % 48;
        short hi = 0, lo = 0;
        if (col < 40) splitbf(W2[row * 40 + col], hi, lo);
        w2h[i] = hi; w2l[i] = lo;
    }
}

// Sentinel row pk1[N]: a_src = -1e30 (-> lrelu_exp = 0 exactly), msg bytes = 0.
static __device__ void dummy_body(unsigned char* __restrict__ pk1, int N) {
    int t = threadIdx.x;
    if (t < 32) {
        unsigned v = ((t & 3) == 0) ? __float_as_uint(-1e30f) : 0u;
        *(unsigned*)(pk1 + (size_t)N * 128 + t * 4) = v;
    }
}

// Layer 1 GEMM via MFMA bf16.  Output = combined 128 B node rows pk1: per head h (0..7),
// 16 B chunk [fp32 a_src(h) | 8 x fp8 msg | 4 B pad].  One row = one cache line.
static __device__ void gemm1_body(const float* __restrict__ x,
                                  const float* __restrict__ W1,
                                  const float* __restrict__ att_s,
                                  const float* __restrict__ att_d,
                                  unsigned char* __restrict__ pk1,
                                  float* __restrict__ a_d1, int N, int gblk) {
    int tid = threadIdx.x, wave = tid >> 6, lane = tid & 63;
    int n16 = lane & 15, q = lane >> 4;
    int nb = gblk * 64 + wave * 16;
    if (nb >= N) return;

    short8 bfr[4][4];
#pragma unroll
    for (int ct = 0; ct < 4; ++ct) {
        int n = ct * 16 + n16;
#pragma unroll
        for (int kc = 0; kc < 4; ++kc) {
            int k0 = kc * 32 + q * 8;
            short8 b;
#pragma unroll
            for (int j = 0; j < 8; ++j) b[j] = f2bf(W1[(k0 + j) * 64 + n]);
            bfr[ct][kc] = b;
        }
    }

    int arow = nb + n16; if (arow >= N) arow = N - 1;
    const float* xr = x + (size_t)arow * 128 + q * 8;
    short8 afr[4];
#pragma unroll
    for (int kc = 0; kc < 4; ++kc) {
        float4 u0 = *(const float4*)(xr + kc * 32);
        float4 u1 = *(const float4*)(xr + kc * 32 + 4);
        short8 a;
        a[0] = f2bf(u0.x); a[1] = f2bf(u0.y); a[2] = f2bf(u0.z); a[3] = f2bf(u0.w);
        a[4] = f2bf(u1.x); a[5] = f2bf(u1.y); a[6] = f2bf(u1.z); a[7] = f2bf(u1.w);
        afr[kc] = a;
    }

    floatx4 acc[4];
#pragma unroll
    for (int ct = 0; ct < 4; ++ct) {
        floatx4 c = {0.f, 0.f, 0.f, 0.f};
#pragma unroll
        for (int kc = 0; kc < 4; ++kc)
            c = __builtin_amdgcn_mfma_f32_16x16x32_bf16(afr[kc], bfr[ct][kc], c, 0, 0, 0);
        acc[ct] = c;
    }

    // message fp8 bytes: channel c = ct*16+n16 -> head h=c>>3, byte h*16 + 4 + (c&7)
#pragma unroll
    for (int ct = 0; ct < 4; ++ct) {
        int h = 2 * ct + (n16 >> 3);
        int cin = n16 & 7;
#pragma unroll
        for (int r = 0; r < 4; ++r) {
            int row = nb + q * 4 + r;
            if (row < N) pk1[(size_t)row * 128 + h * 16 + 4 + cin] = f2fp8(acc[ct][r]);
        }
    }

    // attention logits: a_src fp32 into pk1 chunk head, a_dst fp32 separate
#pragma unroll
    for (int ct = 0; ct < 4; ++ct) {
        float as = att_s[ct * 16 + n16];
        float adv = att_d[ct * 16 + n16];
#pragma unroll
        for (int r = 0; r < 4; ++r) {
            float ps = acc[ct][r] * as;
            float pd = acc[ct][r] * adv;
#pragma unroll
            for (int m = 1; m < 8; m <<= 1) {
                ps += __shfl_xor(ps, m, 64);
                pd += __shfl_xor(pd, m, 64);
            }
            int row = nb + q * 4 + r;
            if ((n16 & 7) == 0 && row < N) {
                int h = 2 * ct + (n16 >> 3);
                a_d1[row * 8 + h] = pd;
                *(float*)(pk1 + (size_t)row * 128 + h * 16) = ps;
            }
        }
    }
}

__global__ __launch_bounds__(256) void k_fuse(const unsigned* __restrict__ packed,
                                              const int* __restrict__ bucketbase,
                                              int* __restrict__ offsets,
                                              int* __restrict__ csr_src,
                                              int N, int NBUK,
                                              const float* __restrict__ W2,
                                              short* __restrict__ w2h,
                                              short* __restrict__ w2l,
                                              const float* __restrict__ x,
                                              const float* __restrict__ W1,
                                              const float* __restrict__ as1,
                                              const float* __restrict__ ad1,
                                              unsigned char* __restrict__ pk1,
                                              float* __restrict__ a_d1) {
    int b = blockIdx.x;
    if (b < NBUK)                fine_body(packed, bucketbase, offsets, csr_src, N, NBUK, b);
    else if (b < NBUK + 12)      splitW2_body(W2, w2h, w2l, b - NBUK);
    else if (b == NBUK + 12)     dummy_body(pk1, N);
    else                         gemm1_body(x, W1, as1, ad1, pk1, a_d1, N, b - NBUK - 13);
}

// ---------------- Layer 1 aggregation: 4-deep pipeline + sentinel + packed f32x2 FMA ---------
__global__ __launch_bounds__(256) void k_agg1(const unsigned char* __restrict__ pk1,
                                              const float* __restrict__ a_d1,
                                              const int* __restrict__ offsets,
                                              const int* __restrict__ csr_src,
                                              const float* __restrict__ b1,
                                              unsigned short* __restrict__ y1b, int N) {
    int wave = threadIdx.x >> 6, lane = threadIdx.x & 63;
    int l32 = lane & 31;         // lane within half
    int e4  = l32 >> 3;          // edge slot (0..3)
    int c8  = l32 & 7;           // head index; owns channels 8*c8 .. 8*c8+7
    int hb  = lane & 32;         // shfl base of this half
    int d = blockIdx.x * 8 + wave * 2 + (lane >> 5);
    bool dval = (d < N);
    int dd = dval ? d : N - 1;   // clamp for safe loads; stores predicated on dval
    float ad = a_d1[dd * 8 + c8];
    floatx2 acc2[4];
#pragma unroll
    for (int k = 0; k < 4; ++k) acc2[k] = (floatx2){0.f, 0.f};
    float wsum = 0.f;
    if (e4 == 0) {               // self-loop handled by edge-slot 0 (8 lanes per half = 8 heads)
        uint4 v = *(const uint4*)(pk1 + (size_t)dd * 128 + c8 * 16);
        float w0 = lrelu_exp(__uint_as_float(v.x) + ad);
        wsum = w0;
        acc2[0] = __builtin_amdgcn_cvt_pk_f32_fp8((int)v.y, false) * w0;
        acc2[1] = __builtin_amdgcn_cvt_pk_f32_fp8((int)v.y, true)  * w0;
        acc2[2] = __builtin_amdgcn_cvt_pk_f32_fp8((int)v.z, false) * w0;
        acc2[3] = __builtin_amdgcn_cvt_pk_f32_fp8((int)v.z, true)  * w0;
    }
    int i0 = offsets[dd], i1 = offsets[dd + 1];
    // Halves may run different trip counts (divergent); all __shfl sources stay within the
    // active half, so inactive-lane reads never occur.
    for (int base = i0; base < i1; base += 32) {
        int idx = base + l32;
        int sv = (idx < i1) ? __builtin_nontemporal_load(csr_src + idx) : N;  // sentinel
        int mh = i1 - base; if (mh > 32) mh = 32;
        // prologue: issue j=0 group's 2 gathers
        int sA = __shfl(sv, hb + e4, 64);
        int sB = __shfl(sv, hb + 4 + e4, 64);
        uint4 vA = *(const uint4*)(pk1 + (size_t)sA * 128 + c8 * 16);
        uint4 vB = *(const uint4*)(pk1 + (size_t)sB * 128 + c8 * 16);
        for (int j = 0; j < mh; j += 8) {
            // prefetch j+8 group (clamped; never consumed if clamped)
            int iC = hb + ((j + 8 + e4 < 32) ? (j + 8 + e4) : 31);
            int iD = hb + ((j + 12 + e4 < 32) ? (j + 12 + e4) : 31);
            int sC = __shfl(sv, iC, 64);
            int sD = __shfl(sv, iD, 64);
            uint4 vC = *(const uint4*)(pk1 + (size_t)sC * 128 + c8 * 16);
            uint4 vD = *(const uint4*)(pk1 + (size_t)sD * 128 + c8 * 16);
            // consume current pair (sentinel rows: a_src=-1e30 -> w=0, msg=0)
            {
                float w = lrelu_exp(__uint_as_float(vA.x) + ad);
                wsum += w;
                acc2[0] = __builtin_amdgcn_cvt_pk_f32_fp8((int)vA.y, false) * w + acc2[0];
                acc2[1] = __builtin_amdgcn_cvt_pk_f32_fp8((int)vA.y, true)  * w + acc2[1];
                acc2[2] = __builtin_amdgcn_cvt_pk_f32_fp8((int)vA.z, false) * w + acc2[2];
                acc2[3] = __builtin_amdgcn_cvt_pk_f32_fp8((int)vA.z, true)  * w + acc2[3];
            }
            {
                float w = lrelu_exp(__uint_as_float(vB.x) + ad);
                wsum += w;
                acc2[0] = __builtin_amdgcn_cvt_pk_f32_fp8((int)vB.y, false) * w + acc2[0];
                acc2[1] = __builtin_amdgcn_cvt_pk_f32_fp8((int)vB.y, true)  * w + acc2[1];
                acc2[2] = __builtin_amdgcn_cvt_pk_f32_fp8((int)vB.z, false) * w + acc2[2];
                acc2[3] = __builtin_amdgcn_cvt_pk_f32_fp8((int)vB.z, true)  * w + acc2[3];
            }
            vA = vC; vB = vD;
        }
    }
    // combine the 4 edge slots within each half (xor 8,16 stays inside the half)
#pragma unroll
    for (int o = 8; o <= 16; o <<= 1) {
#pragma unroll
        for (int k = 0; k < 4; ++k) {
            acc2[k][0] += __shfl_xor(acc2[k][0], o, 64);
            acc2[k][1] += __shfl_xor(acc2[k][1], o, 64);
        }
        wsum += __shfl_xor(wsum, o, 64);
    }
    if (e4 == 0 && dval) {
        float inv = 1.f / (wsum + 1e-16f);
        short8 o8;
#pragma unroll
        for (int k = 0; k < 4; ++k) {
#pragma unroll
            for (int u = 0; u < 2; ++u) {
                float v = acc2[k][u] * inv + b1[c8 * 8 + 2 * k + u];
                v = v > 0.f ? v : expm1f(v);
                o8[2 * k + u] = f2bf(v);
            }
        }
        __builtin_nontemporal_store(o8, (short8*)(y1b + (size_t)d * 64 + c8 * 8));
    }
}

// ---------------- Layer 2 GEMM: y1 bf16 A-frags direct (no splitbf), W2 split-bf16 -----------
__global__ __launch_bounds__(256) void k_gemm2(const unsigned short* __restrict__ y1b,
                                               const short* __restrict__ w2h,
                                               const short* __restrict__ w2l,
                                               const float* __restrict__ att_s,
                                               const float* __restrict__ att_d,
                                               unsigned char* __restrict__ h2b8,
                                               float* __restrict__ a2s,
                                               float* __restrict__ a2d, int N) {
    int tid = threadIdx.x, wave = tid >> 6, lane = tid & 63;
    int n16 = lane & 15, q = lane >> 4;
    int nb = blockIdx.x * 64 + wave * 16;
    if (nb >= N) return;

    int arow = nb + n16; if (arow >= N) arow = N - 1;
    const unsigned short* yr = y1b + (size_t)arow * 64 + q * 8;
    short8 a0 = *(const short8*)(yr);
    short8 a1 = *(const short8*)(yr + 32);

    float psr[4] = {0.f, 0.f, 0.f, 0.f}, pdr[4] = {0.f, 0.f, 0.f, 0.f};
#pragma unroll
    for (int ct = 0; ct < 3; ++ct) {
        int n = ct * 16 + n16;
        short8 bh0, bh1, bl0, bl1;
#pragma unroll
        for (int j = 0; j < 8; ++j) {
            int k0 = q * 8 + j;
            bh0[j] = w2h[k0 * 48 + n];
            bl0[j] = w2l[k0 * 48 + n];
            bh1[j] = w2h[(32 + k0) * 48 + n];
            bl1[j] = w2l[(32 + k0) * 48 + n];
        }
        floatx4 c = {0.f, 0.f, 0.f, 0.f};
        c = __builtin_amdgcn_mfma_f32_16x16x32_bf16(a0, bl0, c, 0, 0, 0);
        c = __builtin_amdgcn_mfma_f32_16x16x32_bf16(a1, bl1, c, 0, 0, 0);
        c = __builtin_amdgcn_mfma_f32_16x16x32_bf16(a0, bh0, c, 0, 0, 0);
        c = __builtin_amdgcn_mfma_f32_16x16x32_bf16(a1, bh1, c, 0, 0, 0);

        int col = ct * 16 + n16;
#pragma unroll
        for (int r = 0; r < 4; ++r) {
            int row = nb + q * 4 + r;
            if (col < 40 && row < N) h2b8[(size_t)row * 40 + col] = f2fp8(c[r]);
        }
        float asv = (col < 40) ? att_s[col] : 0.f;
        float adv = (col < 40) ? att_d[col] : 0.f;
#pragma unroll
        for (int r = 0; r < 4; ++r) {
            psr[r] = fmaf(c[r], asv, psr[r]);
            pdr[r] = fmaf(c[r], adv, pdr[r]);
        }
    }
#pragma unroll
    for (int r = 0; r < 4; ++r) {
        float ps = psr[r], pd = pdr[r];
#pragma unroll
        for (int m = 1; m < 16; m <<= 1) {
            ps += __shfl_xor(ps, m, 64);
            pd += __shfl_xor(pd, m, 64);
        }
        int row = nb + q * 4 + r;
        if (n16 == 0 && row < N) { a2s[row] = ps; a2d[row] = pd; }
    }
}

// ---------------- Layer 2 aggregation: 4-deep pipeline, mask-free, packed f32x2 FMA ----------
__global__ __launch_bounds__(256) void k_agg2(const unsigned char* __restrict__ h2b8,
                                              const float* __restrict__ a2s,
                                              const float* __restrict__ a2d,
                                              const int* __restrict__ offsets,
                                              const int* __restrict__ csr_src,
                                              const float* __restrict__ b2,
                                              float* __restrict__ out, int N) {
    int wave = threadIdx.x >> 6, lane = threadIdx.x & 63;
    int l32 = lane & 31;
    int hb  = lane & 32;              // shfl base of this half
    int t   = l32 / 10;               // edge slot 0..2; t==3 -> lanes 30,31 (acc unused)
    int c10 = l32 % 10;               // channel quad 4*c10 .. 4*c10+3
    int d = blockIdx.x * 8 + wave * 2 + (lane >> 5);
    bool dval = (d < N);
    int dd = dval ? d : N - 1;
    float ad = a2d[dd];
    float w0 = lrelu_exp(a2s[dd] + ad);
    floatx2 acc2[2];
    acc2[0] = (floatx2){0.f, 0.f}; acc2[1] = (floatx2){0.f, 0.f};
    if (t == 0) {                     // self-loop on slot 0 (10 lanes cover 40 channels)
        unsigned v = *(const unsigned*)(h2b8 + (size_t)dd * 40 + c10 * 4);
        acc2[0] = __builtin_amdgcn_cvt_pk_f32_fp8((int)v, false) * w0;
        acc2[1] = __builtin_amdgcn_cvt_pk_f32_fp8((int)v, true)  * w0;
    }
    float wsum_l = 0.f;
    int i0 = offsets[dd], i1 = offsets[dd + 1];
    for (int base = i0; base < i1; base += 30) {
        int m = i1 - base; if (m > 30) m = 30;
        int sv = 0; float wv = 0.f;
        if (l32 < m) {
            sv = __builtin_nontemporal_load(csr_src + base + l32);
            wv = lrelu_exp(a2s[sv] + ad);
        }
        wsum_l += wv;
        // prologue: issue j=0 pair (slots t, 3+t)
        int sA = __shfl(sv, hb + t, 64);
        int sB = __shfl(sv, hb + 3 + t, 64);
        float wA = __shfl(wv, hb + t, 64);
        float wB = __shfl(wv, hb + 3 + t, 64);
        unsigned vA = *(const unsigned*)(h2b8 + (size_t)sA * 40 + c10 * 4);
        unsigned vB = *(const unsigned*)(h2b8 + (size_t)sB * 40 + c10 * 4);
        for (int j = 0; j < m; j += 6) {
            // prefetch j+6 pair (clamped; clamped ones never consumed, and slot 31 has wv=0)
            int iC = hb + ((j + 6 + t < 32) ? (j + 6 + t) : 31);
            int iD = hb + ((j + 9 + t < 32) ? (j + 9 + t) : 31);
            int sC = __shfl(sv, iC, 64);
            int sD = __shfl(sv, iD, 64);
            float wC = __shfl(wv, iC, 64);
            float wD = __shfl(wv, iD, 64);
            unsigned vC = *(const unsigned*)(h2b8 + (size_t)sC * 40 + c10 * 4);
            unsigned vD = *(const unsigned*)(h2b8 + (size_t)sD * 40 + c10 * 4);
            acc2[0] = __builtin_amdgcn_cvt_pk_f32_fp8((int)vA, false) * wA + acc2[0];
            acc2[1] = __builtin_amdgcn_cvt_pk_f32_fp8((int)vA, true)  * wA + acc2[1];
            acc2[0] = __builtin_amdgcn_cvt_pk_f32_fp8((int)vB, false) * wB + acc2[0];
            acc2[1] = __builtin_amdgcn_cvt_pk_f32_fp8((int)vB, true)  * wB + acc2[1];
            vA = vC; vB = vD; wA = wC; wB = wD;
        }
    }
    // wsum over the half (xor strides < 32 stay inside the half)
#pragma unroll
    for (int mm = 1; mm < 32; mm <<= 1) wsum_l += __shfl_xor(wsum_l, mm, 64);
    float wsum = wsum_l + w0;
    // combine 3 edge slots: t==0 lanes gather from t=1 (+10) and t=2 (+20)
#pragma unroll
    for (int k = 0; k < 2; ++k) {
#pragma unroll
        for (int u = 0; u < 2; ++u) {
            float a = acc2[k][u];
            acc2[k][u] = a + __shfl(a, hb + c10 + 10, 64) + __shfl(a, hb + c10 + 20, 64);
        }
    }
    bool act = (t == 0) && dval;
    float inv = 1.f / (wsum + 1e-16f);
    float o[4], mx = -INFINITY;
#pragma unroll
    for (int k = 0; k < 4; ++k) {
        o[k] = act ? (acc2[k >> 1][k & 1] * inv + b2[c10 * 4 + k]) : -INFINITY;
        mx = fmaxf(mx, o[k]);
    }
#pragma unroll
    for (int mm = 1; mm < 32; mm <<= 1) mx = fmaxf(mx, __shfl_xor(mx, mm, 64));
    float ex = 0.f;
    if (act) {
#pragma unroll
        for (int k = 0; k < 4; ++k) ex += __expf(o[k] - mx);
    }
#pragma unroll
    for (int mm = 1; mm < 32; mm <<= 1) ex += __shfl_xor(ex, mm, 64);
    if (act) {
        float lse = __logf(ex);
        floatx4 o4 = {o[0] - mx - lse, o[1] - mx - lse, o[2] - mx - lse, o[3] - mx - lse};
        __builtin_nontemporal_store(o4, (floatx4*)(out + (size_t)d * 40 + c10 * 4));
    }
}

// ---------------- launcher ----------------

extern "C" void kernel_launch(void* const* d_in, const int* in_sizes, int n_in,
                              void* d_out, int out_size, void* d_ws, size_t ws_size,
                              hipStream_t stream) {
    const float* x   = (const float*)d_in[0];
    const int*   ei  = (const int*)d_in[1];
    const float* W1  = (const float*)d_in[2];
    const float* as1 = (const float*)d_in[3];
    const float* ad1 = (const float*)d_in[4];
    const float* b1  = (const float*)d_in[5];
    const float* W2  = (const float*)d_in[6];
    const float* as2 = (const float*)d_in[7];
    const float* ad2 = (const float*)d_in[8];
    const float* b2  = (const float*)d_in[9];
    float* out = (float*)d_out;

    int N = in_sizes[0] / 128;   // 100000
    int E = in_sizes[1] / 2;     // 1600000
    const int* src = ei;
    const int* dst = ei + E;

    int NBUK = (N + 255) >> BSHIFT;          // 391
    int CHUNK = 4096;
    int NBLK = (E + CHUNK - 1) / CHUNK;      // 391

    char* ws = (char*)d_ws;
    size_t off = 0;
    auto alloc = [&](size_t bytes) -> char* {
        char* p = ws + off;
        off += (bytes + 255) & ~(size_t)255;
        return p;
    };
    unsigned char* pk1 = (unsigned char*)alloc((size_t)(N + 1) * 128);  // + sentinel row
    float* a_d1    = (float*)alloc((size_t)N * 8 * 4);
    unsigned short* y1b = (unsigned short*)alloc((size_t)N * 64 * 2);   // bf16
    // h2b8 (fp8, 4 MB) and packed (uint, 6.4 MB) are temporally disjoint: share region.
    size_t shared_sz = (size_t)N * 40;
    if ((size_t)E * 4 > shared_sz) shared_sz = (size_t)E * 4;
    char*  region  = alloc(shared_sz);
    unsigned char* h2b8 = (unsigned char*)region;
    unsigned* packed    = (unsigned*)region;
    float* a2s     = (float*)alloc((size_t)N * 4);
    float* a2d     = (float*)alloc((size_t)N * 4);
    int*   offsets = (int*)alloc((size_t)(N + 1) * 4);
    int*   csr_src = (int*)alloc((size_t)E * 4);
    int*   blockhist  = (int*)alloc((size_t)NBUK * NBLK * 4);
    int*   btot       = (int*)alloc((size_t)NBUK * 4);
    int*   bucketbase = (int*)alloc((size_t)(NBUK + 1) * 4);
    short* w2h     = (short*)alloc((size_t)64 * 48 * 2);
    short* w2l     = (short*)alloc((size_t)64 * 48 * 2);

    int nb2 = (N + 7) / 8;   // agg kernels: 2 nodes per wave, 8 per block
    int gb = (N + 63) / 64;

    k_hist<<<NBLK, 512, 0, stream>>>(dst, E, CHUNK, NBLK, NBUK, blockhist);
    k_colscan<<<NBUK, 256, 0, stream>>>(blockhist, btot, NBLK);
    k_bucket_scan<<<1, 512, 0, stream>>>(btot, bucketbase, NBUK);
    k_partition<<<NBLK, 512, 0, stream>>>(src, dst, E, CHUNK, NBLK, NBUK, blockhist,
                                          bucketbase, packed);
    // fused: fine (NBUK) + splitW2 (12) + sentinel (1) + gemm1 (gb) — compiles gemm1 clean
    k_fuse<<<NBUK + 13 + gb, 256, 0, stream>>>(packed, bucketbase, offsets, csr_src, N, NBUK,
                                               W2, w2h, w2l, x, W1, as1, ad1,
                                               pk1, a_d1);
    k_agg1<<<nb2, 256, 0, stream>>>(pk1, a_d1, offsets, csr_src, b1, y1b, N);
    k_gemm2<<<gb, 256, 0, stream>>>(y1b, w2h, w2l, as2, ad2, h2b8, a2s, a2d, N);
    k_agg2<<<nb2, 256, 0, stream>>>(h2b8, a2s, a2d, offsets, csr_src, b2, out, N);
}